// Round 6
// baseline (502.574 us; speedup 1.0000x reference)
//
#include <hip/hip_runtime.h>
#include <cstdint>
#include <cstddef>

using u16 = unsigned short;

typedef __attribute__((ext_vector_type(4))) float f32x4;
typedef __attribute__((ext_vector_type(8))) short bf16x8;

#define DEV static __device__ __forceinline__

DEV float bf2f(u16 v) {
  union { unsigned u; float f; } x; x.u = ((unsigned)v) << 16; return x.f;
}
DEV u16 f2bf(float f) {
  union { float f; unsigned u; } x; x.f = f;
  unsigned r = x.u + 0x7fffu + ((x.u >> 16) & 1u);
  return (u16)(r >> 16);
}
DEV void gload16(const void* g, void* l) {
  __builtin_amdgcn_global_load_lds((const __attribute__((address_space(1))) void*)g,
                                   (__attribute__((address_space(3))) void*)l, 16, 0, 0);
}
DEV float fast_gelu(float x) {
  // jax.nn.gelu tanh-form; tanh via exp2+rcp (no div sequence, no clamps:
  // e->inf => t=1, e->0 => t=-1, both correct limits)
  const float y = 0.7978845608028654f * (x + 0.044715f * x * x * x);
  const float e = __builtin_amdgcn_exp2f(y * 2.8853900817779268f);  // exp(2y)
  const float t = 1.0f - 2.0f * __builtin_amdgcn_rcpf(e + 1.0f);
  return 0.5f * x * (1.0f + t);
}

// max-reduce across the 16-lane m15 dimension via DPP row rotations (VALU only)
DEV float rowmax16_dpp(float v) {
  union { float f; int i; } a, b;
  a.f = v;
  b.i = __builtin_amdgcn_update_dpp(0, a.i, 0x121, 0xf, 0xf, true); a.f = fmaxf(a.f, b.f);
  b.i = __builtin_amdgcn_update_dpp(0, a.i, 0x122, 0xf, 0xf, true); a.f = fmaxf(a.f, b.f);
  b.i = __builtin_amdgcn_update_dpp(0, a.i, 0x124, 0xf, 0xf, true); a.f = fmaxf(a.f, b.f);
  b.i = __builtin_amdgcn_update_dpp(0, a.i, 0x128, 0xf, 0xf, true); a.f = fmaxf(a.f, b.f);
  return a.f;
}

// ---------------------------------------------------------------------------
// NT GEMM: C[M,N] = A[M,K] (row-major bf16) x Bt[N,K] (row-major bf16) + epilogue
// 128xBN tile, BK=32, 256 threads (4 waves), mfma 16x16x32 bf16.
// launch_bounds(256,4): cap regs at 128/wave (56 VGPR + 64 AGPR fits) -> 4 blk/CU.
// SPLIT: split-K over blockIdx.z; slice ks writes bf16 partial at C + ks*sC.
// ---------------------------------------------------------------------------
template <typename OutT, bool GELU, int BN, bool SPLIT>
__global__ __launch_bounds__(256, 4) void gemm_nt(
    const u16* __restrict__ A, const u16* __restrict__ Bt, OutT* __restrict__ C,
    int K, int lda, int ldb, int ldc,
    const float* __restrict__ bias,
    const float* __restrict__ resF, const u16* __restrict__ resB, int ldr,
    float scale,
    long long sA, long long sB, long long sC, long long sR,
    int kSlices)
{
  constexpr int NW = (BN == 128) ? 64 : 32;   // wave n-extent
  constexpr int NJ = NW / 16;
  __shared__ u16 As[128 * 32];
  __shared__ u16 Bs[BN * 32];

  const int z = blockIdx.z;
  const int bz = z / kSlices;
  const int ks = z - bz * kSlices;
  const int Ksl = K / kSlices;
  const int kbeg = ks * Ksl, kend = kbeg + Ksl;

  A  += (size_t)bz * sA;
  Bt += (size_t)bz * sB;
  if constexpr (SPLIT) C += (size_t)ks * sC;
  else                 C += (size_t)bz * sC;
  const int m0 = blockIdx.y * 128, n0 = blockIdx.x * BN;
  const int tid = threadIdx.x;
  const int lane = tid & 63, wave = tid >> 6;
  const int wm = (wave >> 1) * 64, wn = (wave & 1) * NW;
  const int m15 = lane & 15, quad = lane >> 4;

  const u16* Ab = A + (size_t)m0 * lda;
  const u16* Bb = Bt + (size_t)n0 * ldb;
  const int r0 = tid >> 2, cc8 = (tid & 3) * 8;

  f32x4 acc[4][NJ];
#pragma unroll
  for (int i = 0; i < 4; i++)
#pragma unroll
    for (int j = 0; j < NJ; j++) acc[i][j] = (f32x4){0.f, 0.f, 0.f, 0.f};

  for (int k0 = kbeg; k0 < kend; k0 += 32) {
    __syncthreads();
    gload16(Ab + (size_t)r0 * lda + k0 + cc8,        &As[tid * 8]);
    gload16(Ab + (size_t)(r0 + 64) * lda + k0 + cc8, &As[2048 + tid * 8]);
    gload16(Bb + (size_t)r0 * ldb + k0 + cc8,        &Bs[tid * 8]);
    if constexpr (BN == 128)
      gload16(Bb + (size_t)(r0 + 64) * ldb + k0 + cc8, &Bs[2048 + tid * 8]);
    __syncthreads();
    bf16x8 af[4], bfr[NJ];
#pragma unroll
    for (int i = 0; i < 4; i++) af[i]  = *(const bf16x8*)&As[(wm + i * 16 + m15) * 32 + quad * 8];
#pragma unroll
    for (int j = 0; j < NJ; j++) bfr[j] = *(const bf16x8*)&Bs[(wn + j * 16 + m15) * 32 + quad * 8];
#pragma unroll
    for (int i = 0; i < 4; i++)
#pragma unroll
      for (int j = 0; j < NJ; j++)
        acc[i][j] = __builtin_amdgcn_mfma_f32_16x16x32_bf16(af[i], bfr[j], acc[i][j], 0, 0, 0);
  }

  const float* resFb = resF ? resF + (size_t)bz * sR : nullptr;
  const u16*   resBb = resB ? resB + (size_t)bz * sR : nullptr;

#pragma unroll
  for (int i = 0; i < 4; i++) {
    const int rowb = m0 + wm + i * 16 + quad * 4;
#pragma unroll
    for (int r = 0; r < 4; r++) {
      const size_t rowoff = (size_t)(rowb + r) * ldc;
      const size_t resoff = (size_t)(rowb + r) * ldr;
#pragma unroll
      for (int j = 0; j < NJ; j++) {
        const int col = n0 + wn + j * 16 + m15;
        float v = acc[i][j][r] * scale;
        if constexpr (SPLIT) {
          ((u16*)C)[rowoff + col] = f2bf(v);
        } else {
          if (bias) v += bias[col];
          if (GELU) v = fast_gelu(v);
          if (resFb) v += resFb[resoff + col];
          if (resBb) v += bf2f(resBb[resoff + col]);
          if constexpr (sizeof(OutT) == 4) C[rowoff + col] = v;
          else ((u16*)C)[rowoff + col] = f2bf(v);
        }
      }
    }
  }
}

// ---------------------------------------------------------------------------
// mlp2 reduce: outF = sum_{ks<4} partial[ks] + outb(bf16 residual) + b_m2[col]
// ---------------------------------------------------------------------------
__global__ __launch_bounds__(256) void mlp2_reduce_k(
    const u16* __restrict__ part, long long sliceStride,
    const u16* __restrict__ outb, const float* __restrict__ b_m2,
    float* __restrict__ outF)
{
  const size_t i = (size_t)blockIdx.x * 256 + threadIdx.x;
  const int col = (int)((i * 4) & 1023);
  const ushort4 u = ((const ushort4*)outb)[i];
  float4 o;
  o.x = bf2f(u.x) + b_m2[col + 0];
  o.y = bf2f(u.y) + b_m2[col + 1];
  o.z = bf2f(u.z) + b_m2[col + 2];
  o.w = bf2f(u.w) + b_m2[col + 3];
#pragma unroll
  for (int ks = 0; ks < 4; ks++) {
    const ushort4 p = ((const ushort4*)(part + (size_t)ks * sliceStride))[i];
    o.x += bf2f(p.x); o.y += bf2f(p.y); o.z += bf2f(p.z); o.w += bf2f(p.w);
  }
  ((float4*)outF)[i] = o;
}

// ---------------------------------------------------------------------------
// Fused weight transposes fp32->bf16: all 5 weights in one launch.
// ---------------------------------------------------------------------------
__global__ __launch_bounds__(256) void transpose_all_k(
    const float* __restrict__ w_qkv, const float* __restrict__ w_o,
    const float* __restrict__ w_kv,  const float* __restrict__ w_m1,
    const float* __restrict__ w_m2,
    u16* __restrict__ wqkvT, u16* __restrict__ woT, u16* __restrict__ wkvT,
    u16* __restrict__ wm1T,  u16* __restrict__ wm2T)
{
  __shared__ u16 tile[32][33];
  int idx = blockIdx.x;
  const float* in; u16* out; int gx, ldin, ldout;
  if (idx < 3072)      { in = w_qkv; out = wqkvT; gx = 96;  ldin = 3072; ldout = 1024; }
  else if (idx < 4096) { idx -= 3072; in = w_o;  out = woT;  gx = 32;  ldin = 1024; ldout = 1024; }
  else if (idx < 6144) { idx -= 4096; in = w_kv; out = wkvT; gx = 64;  ldin = 2048; ldout = 1024; }
  else if (idx < 10240){ idx -= 6144; in = w_m1; out = wm1T; gx = 128; ldin = 4096; ldout = 1024; }
  else                 { idx -= 10240; in = w_m2; out = wm2T; gx = 32; ldin = 1024; ldout = 4096; }
  const int bx = idx % gx, by = idx / gx;
  const int tx = threadIdx.x & 31, ty = threadIdx.x >> 5;
  const int x = bx * 32 + tx;
#pragma unroll
  for (int j = 0; j < 4; j++)
    tile[ty + j * 8][tx] = f2bf(in[(size_t)(by * 32 + ty + j * 8) * ldin + x]);
  __syncthreads();
  const int x2 = by * 32 + tx;
#pragma unroll
  for (int j = 0; j < 4; j++)
    out[(size_t)(bx * 32 + ty + j * 8) * ldout + x2] = tile[tx][ty + j * 8];
}

// ---------------------------------------------------------------------------
// Fused prep: blockIdx.y==0 -> xln = layernorm(x,g1,b1); ==1 -> zb = bf16(z)
// grid (4096, 2)
// ---------------------------------------------------------------------------
__global__ __launch_bounds__(256) void prep_k(
    const float* __restrict__ x, const float* __restrict__ g, const float* __restrict__ bb,
    u16* __restrict__ xln, const float* __restrict__ z, u16* __restrict__ zb)
{
  const int row = blockIdx.x;
  const int t = threadIdx.x;
  if (blockIdx.y == 1) {
    const size_t i = (size_t)row * 256 + t;
    const float4 f = ((const float4*)z)[i];
    ushort4 o; o.x = f2bf(f.x); o.y = f2bf(f.y); o.z = f2bf(f.z); o.w = f2bf(f.w);
    ((ushort4*)zb)[i] = o;
    return;
  }
  float v[4];
  const float4 f = ((const float4*)(x + (size_t)row * 1024))[t];
  v[0] = f.x; v[1] = f.y; v[2] = f.z; v[3] = f.w;
  float s = v[0] + v[1] + v[2] + v[3];
  float sq = v[0]*v[0] + v[1]*v[1] + v[2]*v[2] + v[3]*v[3];
#pragma unroll
  for (int off = 1; off < 64; off <<= 1) { s += __shfl_xor(s, off); sq += __shfl_xor(sq, off); }
  __shared__ float red[8];
  const int wv = t >> 6;
  if ((t & 63) == 0) { red[wv] = s; red[4 + wv] = sq; }
  __syncthreads();
  s = red[0] + red[1] + red[2] + red[3];
  sq = red[4] + red[5] + red[6] + red[7];
  const float mean = s * (1.0f / 1024.0f);
  const float var = sq * (1.0f / 1024.0f) - mean * mean;
  const float rstd = rsqrtf(var + 1e-5f);
  const int c = t * 4;
  ushort4 o;
  o.x = f2bf((v[0] - mean) * rstd * g[c + 0] + bb[c + 0]);
  o.y = f2bf((v[1] - mean) * rstd * g[c + 1] + bb[c + 1]);
  o.z = f2bf((v[2] - mean) * rstd * g[c + 2] + bb[c + 2]);
  o.w = f2bf((v[3] - mean) * rstd * g[c + 3] + bb[c + 3]);
  ((ushort4*)(xln + (size_t)row * 1024))[t] = o;
}

// ---------------------------------------------------------------------------
// V pre-transpose for self-attention: per (b,h), [1024 keys][64 d] -> [64 d][1024 keys]
// grid (32, 2, 64)
// ---------------------------------------------------------------------------
__global__ __launch_bounds__(256) void transpose_v_self(
    const u16* __restrict__ qkv, u16* __restrict__ vT)
{
  __shared__ u16 tile[32][33];
  const int z = blockIdx.z, b = z >> 4, h = z & 15;
  const u16* in = qkv + (size_t)b * 1024 * 3072 + 2048 + h * 64;
  u16* out = vT + (size_t)z * 64 * 1024;
  const int tx = threadIdx.x & 31, ty = threadIdx.x >> 5;
  const int key0 = blockIdx.x * 32, d0 = blockIdx.y * 32;
#pragma unroll
  for (int j = 0; j < 4; j++)
    tile[ty + j * 8][tx] = in[(size_t)(key0 + ty + j * 8) * 3072 + d0 + tx];
  __syncthreads();
#pragma unroll
  for (int j = 0; j < 4; j++)
    out[(size_t)(d0 + ty + j * 8) * 1024 + key0 + tx] = tile[tx][ty + j * 8];
}

// ---------------------------------------------------------------------------
// Flash self-attention v3: 64 q-rows/block, grid (16,16,4)=1024 blocks.
// ---------------------------------------------------------------------------
__global__ __launch_bounds__(256, 5) void flash_self_attn3(
    const u16* __restrict__ qkv, const u16* __restrict__ vT, u16* __restrict__ outp)
{
  __shared__ u16 Ks[64 * 72];
  __shared__ u16 Vs[64 * 72];
  __shared__ u16 Ps[4][16 * 72];
  const int b = blockIdx.z, h = blockIdx.y, q0 = blockIdx.x * 64;
  const int tid = threadIdx.x;
  const int lane = tid & 63, w = tid >> 6;
  const int m15 = lane & 15, quad = lane >> 4;
  const float L2E = 1.4426950408889634f;

  const size_t base = (size_t)b * 1024 * 3072;
  const u16* qb  = qkv + base + (size_t)q0 * 3072 + h * 64;
  const u16* kb  = qkv + base + 1024 + h * 64;
  const u16* vtb = vT + (size_t)(b * 16 + h) * 64 * 1024;

  const int r8 = tid >> 3, c8 = (tid & 7) * 8;

  bf16x8 aq[2];
#pragma unroll
  for (int kk = 0; kk < 2; kk++) {
    const bf16x8 raw = *(const bf16x8*)(qb + (size_t)(w * 16 + m15) * 3072 + kk * 32 + quad * 8);
#pragma unroll
    for (int j = 0; j < 8; j++)
      ((u16*)&aq[kk])[j] = f2bf(bf2f(((const u16*)&raw)[j]) * 0.125f);
  }

  const short oneb = (short)0x3F80;
  const bf16x8 ones = {oneb, oneb, oneb, oneb, oneb, oneb, oneb, oneb};

  float mL[4];
  f32x4 lacc;
  f32x4 oacc[4];
#pragma unroll
  for (int r = 0; r < 4; r++) mL[r] = -3.0e38f;
  lacc = (f32x4){0.f, 0.f, 0.f, 0.f};
#pragma unroll
  for (int d = 0; d < 4; d++) oacc[d] = (f32x4){0.f, 0.f, 0.f, 0.f};

  for (int kt = 0; kt < 16; kt++) {
    const int key0 = kt * 64;
    bf16x8 kreg[2], vreg[2];
#pragma unroll
    for (int i = 0; i < 2; i++) {
      kreg[i] = *(const bf16x8*)(kb + (size_t)(key0 + r8 + i * 32) * 3072 + c8);
      vreg[i] = *(const bf16x8*)(vtb + (size_t)(r8 + i * 32) * 1024 + key0 + c8);
    }
    __syncthreads();
#pragma unroll
    for (int i = 0; i < 2; i++) {
      *(bf16x8*)&Ks[(r8 + i * 32) * 72 + c8] = kreg[i];
      *(bf16x8*)&Vs[(r8 + i * 32) * 72 + c8] = vreg[i];
    }
    __syncthreads();

    f32x4 sacc[4];
#pragma unroll
    for (int n = 0; n < 4; n++) sacc[n] = (f32x4){0.f, 0.f, 0.f, 0.f};
#pragma unroll
    for (int kk = 0; kk < 2; kk++)
#pragma unroll
      for (int n = 0; n < 4; n++) {
        const bf16x8 bk = *(const bf16x8*)&Ks[(n * 16 + m15) * 72 + kk * 32 + quad * 8];
        sacc[n] = __builtin_amdgcn_mfma_f32_16x16x32_bf16(aq[kk], bk, sacc[n], 0, 0, 0);
      }

    float al[4];
#pragma unroll
    for (int r = 0; r < 4; r++) {
      float v = fmaxf(fmaxf(sacc[0][r], sacc[1][r]), fmaxf(sacc[2][r], sacc[3][r]));
      v = rowmax16_dpp(v) * L2E;
      const float mnew = fmaxf(mL[r], v);
      al[r] = __builtin_amdgcn_exp2f(mL[r] - mnew);
      mL[r] = mnew;
    }
#pragma unroll
    for (int n = 0; n < 4; n++)
#pragma unroll
      for (int r = 0; r < 4; r++) {
        const float p = __builtin_amdgcn_exp2f(fmaf(sacc[n][r], L2E, -mL[r]));
        Ps[w][(quad * 4 + r) * 72 + n * 16 + m15] = f2bf(p);
      }
#pragma unroll
    for (int r = 0; r < 4; r++) {
      lacc[r] *= al[r];
#pragma unroll
      for (int d = 0; d < 4; d++) oacc[d][r] *= al[r];
    }

    bf16x8 ap[2];
    ap[0] = *(const bf16x8*)&Ps[w][m15 * 72 + quad * 8];
    ap[1] = *(const bf16x8*)&Ps[w][m15 * 72 + 32 + quad * 8];
    lacc = __builtin_amdgcn_mfma_f32_16x16x32_bf16(ap[0], ones, lacc, 0, 0, 0);
    lacc = __builtin_amdgcn_mfma_f32_16x16x32_bf16(ap[1], ones, lacc, 0, 0, 0);
#pragma unroll
    for (int kk = 0; kk < 2; kk++)
#pragma unroll
      for (int d = 0; d < 4; d++) {
        const bf16x8 bv = *(const bf16x8*)&Vs[(d * 16 + m15) * 72 + kk * 32 + quad * 8];
        oacc[d] = __builtin_amdgcn_mfma_f32_16x16x32_bf16(ap[kk], bv, oacc[d], 0, 0, 0);
      }
  }

  u16* ob = outp + (size_t)(b * 1024 + q0 + w * 16 + quad * 4) * 1024 + h * 64 + m15;
#pragma unroll
  for (int r = 0; r < 4; r++) {
    const float inv = 1.0f / lacc[r];
#pragma unroll
    for (int d = 0; d < 4; d++)
      ob[(size_t)r * 1024 + d * 16] = f2bf(oacc[d][r] * inv);
  }
}

// ---------------------------------------------------------------------------
// LayerNorm over last dim (1024), bf16 in -> bf16 out (ln2)
// ---------------------------------------------------------------------------
__global__ __launch_bounds__(256) void layernorm_b_k(
    const u16* __restrict__ x, const float* __restrict__ g, const float* __restrict__ bb,
    u16* __restrict__ y)
{
  const int row = blockIdx.x;
  const int t = threadIdx.x;
  float v[4];
  const ushort4 u = ((const ushort4*)(x + (size_t)row * 1024))[t];
  v[0] = bf2f(u.x); v[1] = bf2f(u.y); v[2] = bf2f(u.z); v[3] = bf2f(u.w);
  float s = v[0] + v[1] + v[2] + v[3];
  float sq = v[0]*v[0] + v[1]*v[1] + v[2]*v[2] + v[3]*v[3];
#pragma unroll
  for (int off = 1; off < 64; off <<= 1) { s += __shfl_xor(s, off); sq += __shfl_xor(sq, off); }
  __shared__ float red[8];
  const int wv = t >> 6;
  if ((t & 63) == 0) { red[wv] = s; red[4 + wv] = sq; }
  __syncthreads();
  s = red[0] + red[1] + red[2] + red[3];
  sq = red[4] + red[5] + red[6] + red[7];
  const float mean = s * (1.0f / 1024.0f);
  const float var = sq * (1.0f / 1024.0f) - mean * mean;
  const float rstd = rsqrtf(var + 1e-5f);
  const int c = t * 4;
  ushort4 o;
  o.x = f2bf((v[0] - mean) * rstd * g[c + 0] + bb[c + 0]);
  o.y = f2bf((v[1] - mean) * rstd * g[c + 1] + bb[c + 1]);
  o.z = f2bf((v[2] - mean) * rstd * g[c + 2] + bb[c + 2]);
  o.w = f2bf((v[3] - mean) * rstd * g[c + 3] + bb[c + 3]);
  ((ushort4*)(y + (size_t)row * 1024))[t] = o;
}

// ---------------------------------------------------------------------------
// Row softmax over 1024 fp32 -> bf16 probabilities
// ---------------------------------------------------------------------------
__global__ __launch_bounds__(256) void softmax_rows_k(const float* __restrict__ S, u16* __restrict__ P)
{
  const int row = blockIdx.x;
  const int t = threadIdx.x;
  const float4 f = ((const float4*)(S + (size_t)row * 1024))[t];
  float mx = fmaxf(fmaxf(f.x, f.y), fmaxf(f.z, f.w));
#pragma unroll
  for (int off = 1; off < 64; off <<= 1) mx = fmaxf(mx, __shfl_xor(mx, off));
  __shared__ float red[8];
  const int wv = t >> 6;
  if ((t & 63) == 0) red[wv] = mx;
  __syncthreads();
  mx = fmaxf(fmaxf(red[0], red[1]), fmaxf(red[2], red[3]));
  float e0 = __expf(f.x - mx), e1 = __expf(f.y - mx), e2 = __expf(f.z - mx), e3 = __expf(f.w - mx);
  float s = e0 + e1 + e2 + e3;
#pragma unroll
  for (int off = 1; off < 64; off <<= 1) s += __shfl_xor(s, off);
  if ((t & 63) == 0) red[4 + wv] = s;
  __syncthreads();
  s = red[4] + red[5] + red[6] + red[7];
  const float inv = 1.0f / s;
  ushort4 o; o.x = f2bf(e0 * inv); o.y = f2bf(e1 * inv); o.z = f2bf(e2 * inv); o.w = f2bf(e3 * inv);
  ((ushort4*)(P + (size_t)row * 1024))[t] = o;
}

// ---------------------------------------------------------------------------
// Transpose [R,C] -> [C,R], u16 in/out. grid = (C/32, R/32, batch), block 256.
// ---------------------------------------------------------------------------
__global__ __launch_bounds__(256) void transpose_k(
    const u16* __restrict__ in, u16* __restrict__ out,
    int ldin, int ldout, long long sIn, long long sOut)
{
  __shared__ u16 tile[32][33];
  in  += (size_t)blockIdx.z * sIn;
  out += (size_t)blockIdx.z * sOut;
  const int tx = threadIdx.x & 31, ty = threadIdx.x >> 5;
  const int x = blockIdx.x * 32 + tx;
#pragma unroll
  for (int j = 0; j < 4; j++)
    tile[ty + j * 8][tx] = in[(size_t)(blockIdx.y * 32 + ty + j * 8) * ldin + x];
  __syncthreads();
  const int x2 = blockIdx.y * 32 + tx;
#pragma unroll
  for (int j = 0; j < 4; j++)
    out[(size_t)(blockIdx.x * 32 + ty + j * 8) * ldout + x2] = tile[tx][ty + j * 8];
}

// ---------------------------------------------------------------------------
extern "C" void kernel_launch(void* const* d_in, const int* in_sizes, int n_in,
                              void* d_out, int out_size, void* d_ws, size_t ws_size,
                              hipStream_t stream)
{
  const float* x     = (const float*)d_in[0];   // [4,1024,1024]
  const float* z     = (const float*)d_in[1];   // [4,1024,1024]
  const float* g1    = (const float*)d_in[2];
  const float* b1    = (const float*)d_in[3];
  const float* w_qkv = (const float*)d_in[4];   // [1024,3072]
  const float* b_qkv = (const float*)d_in[5];
  const float* w_o   = (const float*)d_in[6];   // [1024,1024]
  const float* b_o   = (const float*)d_in[7];
  const float* w_kv  = (const float*)d_in[8];   // [1024,2048]
  const float* b_kv  = (const float*)d_in[9];
  const float* g2    = (const float*)d_in[10];
  const float* b2    = (const float*)d_in[11];
  const float* w_m1  = (const float*)d_in[12];  // [1024,4096]
  const float* b_m1  = (const float*)d_in[13];
  const float* w_m2  = (const float*)d_in[14];  // [4096,1024]
  const float* b_m2  = (const float*)d_in[15];
  float* outF = (float*)d_out;                  // [4,1024,1024] fp32

  char* ws = (char*)d_ws;
  const size_t MB = 1024ull * 1024ull;
  u16*   qkv   = (u16*)(ws + 0);         // 24MB (dead after flash)
  u16*   Pm    = (u16*)(ws + 0);         // 8MB (alias)
  u16*   hm    = (u16*)(ws + 0);         // 32MB (alias)
  u16*   zb    = (u16*)(ws + 24 * MB);   // 8MB (dead after kv GEMM)
  u16*   vTs   = (u16*)(ws + 24 * MB);   // 8MB self-attn V^T (alias of zb)
  u16*   xln   = (u16*)(ws + 32 * MB);   // 8MB; reused as attn_out
  u16*   mpart = (u16*)(ws + 32 * MB);   // 32MB: mlp2 bf16 partials x4
  u16*   qbuf  = (u16*)(ws + 40 * MB);   // 8MB
  u16*   kv    = (u16*)(ws + 48 * MB);   // 16MB
  float* Ssc   = (float*)(ws + 64 * MB); // 16MB fp32
  u16*   h1    = (u16*)(ws + 64 * MB);   // 8MB (alias, after Ssc dead)
  u16*   outb  = (u16*)(ws + 80 * MB);   // 8MB
  u16*   wqkvT = (u16*)(ws + 88 * MB);   // 6MB
  u16*   woT   = (u16*)(ws + 94 * MB);   // 2MB
  u16*   wkvT  = (u16*)(ws + 96 * MB);   // 4MB
  u16*   wm1T  = (u16*)(ws + 100 * MB);  // 8MB
  u16*   wm2T  = (u16*)(ws + 108 * MB);  // 8MB
  u16*   vT    = (u16*)(ws + 116 * MB);  // 8MB

  dim3 blk(256);
  const long long M1 = 1024 * 1024;

  hipLaunchKernelGGL(transpose_all_k, dim3(14336), blk, 0, stream,
                     w_qkv, w_o, w_kv, w_m1, w_m2, wqkvT, woT, wkvT, wm1T, wm2T);
  // fused: xln = ln1(x), zb = bf16(z)
  hipLaunchKernelGGL(prep_k, dim3(4096, 2), blk, 0, stream, x, g1, b1, xln, z, zb);

  // kv = z @ w_kv + b_kv   [4096,2048]
  hipLaunchKernelGGL((gemm_nt<u16, false, 128, false>), dim3(16, 32, 1), blk, 0, stream,
                     zb, wkvT, kv, 1024, 1024, 1024, 2048,
                     b_kv, (const float*)nullptr, (const u16*)nullptr, 0, 1.0f, 0LL, 0LL, 0LL, 0LL, 1);
  // qkv = ln1(x) @ w_qkv + b_qkv   [4096,3072]
  hipLaunchKernelGGL((gemm_nt<u16, false, 128, false>), dim3(24, 32, 1), blk, 0, stream,
                     xln, wqkvT, qkv, 1024, 1024, 1024, 3072,
                     b_qkv, (const float*)nullptr, (const u16*)nullptr, 0, 1.0f, 0LL, 0LL, 0LL, 0LL, 1);
  // V^T for self-attention (overwrites zb region)
  hipLaunchKernelGGL(transpose_v_self, dim3(32, 2, 64), blk, 0, stream, qkv, vTs);
  // self-attention -> attn_out (reuses xln buffer)
  hipLaunchKernelGGL(flash_self_attn3, dim3(16, 16, 4), blk, 0, stream, qkv, vTs, xln);
  // q = x + attn_out @ w_o + b_o   [4096,1024]
  hipLaunchKernelGGL((gemm_nt<u16, false, 64, false>), dim3(16, 32, 1), blk, 0, stream,
                     xln, woT, qbuf, 1024, 1024, 1024, 1024,
                     b_o, x, (const u16*)nullptr, 1024, 1.0f, 0LL, 0LL, 0LL, 0LL, 1);
  // cross scores S = q @ k^T / 32  per batch
  hipLaunchKernelGGL((gemm_nt<float, false, 64, false>), dim3(16, 8, 4), blk, 0, stream,
                     qbuf, kv, Ssc, 1024, 1024, 2048, 1024,
                     (const float*)nullptr, (const float*)nullptr, (const u16*)nullptr, 0,
                     0.03125f, M1, 2 * M1, M1, 0LL, 1);
  hipLaunchKernelGGL(softmax_rows_k, dim3(4096), blk, 0, stream, Ssc, Pm);
  // vT per batch (v = kv[:, 1024:2048])
  hipLaunchKernelGGL(transpose_k, dim3(32, 32, 4), blk, 0, stream,
                     kv + 1024, vT, 2048, 1024, 2 * M1, M1);
  // out = P @ v   [4,1024,1024]
  hipLaunchKernelGGL((gemm_nt<u16, false, 64, false>), dim3(16, 8, 4), blk, 0, stream,
                     Pm, vT, outb, 1024, 1024, 1024, 1024,
                     (const float*)nullptr, (const float*)nullptr, (const u16*)nullptr, 0,
                     1.0f, M1, M1, M1, 0LL, 1);
  // h1 = ln2(out)
  hipLaunchKernelGGL(layernorm_b_k, dim3(4096), blk, 0, stream, (const u16*)outb, g2, b2, h1);
  // hm = gelu(h1 @ w_m1 + b_m1)  [4096,4096]
  hipLaunchKernelGGL((gemm_nt<u16, true, 128, false>), dim3(32, 32, 1), blk, 0, stream,
                     h1, wm1T, hm, 1024, 1024, 1024, 4096,
                     b_m1, (const float*)nullptr, (const u16*)nullptr, 0, 1.0f, 0LL, 0LL, 0LL, 0LL, 1);
  // mlp2 split-K=4: bf16 partials (1024 blocks), then fused reduce
  hipLaunchKernelGGL((gemm_nt<u16, false, 128, true>), dim3(8, 32, 4), blk, 0, stream,
                     hm, wm2T, mpart, 4096, 4096, 4096, 1024,
                     (const float*)nullptr, (const float*)nullptr, (const u16*)nullptr, 0,
                     1.0f, 0LL, 0LL, 4LL * M1, 0LL, 4);
  hipLaunchKernelGGL(mlp2_reduce_k, dim3(4096), blk, 0, stream,
                     mpart, 4LL * M1, outb, b_m2, outF);
}

// Round 7
// 463.921 us; speedup vs baseline: 1.0833x; 1.0833x over previous
//
#include <hip/hip_runtime.h>
#include <cstdint>
#include <cstddef>

using u16 = unsigned short;

typedef __attribute__((ext_vector_type(4))) float f32x4;
typedef __attribute__((ext_vector_type(8))) short bf16x8;

#define DEV static __device__ __forceinline__

DEV float bf2f(u16 v) {
  union { unsigned u; float f; } x; x.u = ((unsigned)v) << 16; return x.f;
}
DEV u16 f2bf(float f) {
  union { float f; unsigned u; } x; x.f = f;
  unsigned r = x.u + 0x7fffu + ((x.u >> 16) & 1u);
  return (u16)(r >> 16);
}
DEV void gload16(const void* g, void* l) {
  __builtin_amdgcn_global_load_lds((const __attribute__((address_space(1))) void*)g,
                                   (__attribute__((address_space(3))) void*)l, 16, 0, 0);
}
DEV float fast_gelu(float x) {
  const float y = 0.7978845608028654f * (x + 0.044715f * x * x * x);
  const float e = __builtin_amdgcn_exp2f(y * 2.8853900817779268f);  // exp(2y)
  const float t = 1.0f - 2.0f * __builtin_amdgcn_rcpf(e + 1.0f);
  return 0.5f * x * (1.0f + t);
}

DEV float rowmax16_dpp(float v) {
  union { float f; int i; } a, b;
  a.f = v;
  b.i = __builtin_amdgcn_update_dpp(0, a.i, 0x121, 0xf, 0xf, true); a.f = fmaxf(a.f, b.f);
  b.i = __builtin_amdgcn_update_dpp(0, a.i, 0x122, 0xf, 0xf, true); a.f = fmaxf(a.f, b.f);
  b.i = __builtin_amdgcn_update_dpp(0, a.i, 0x124, 0xf, 0xf, true); a.f = fmaxf(a.f, b.f);
  b.i = __builtin_amdgcn_update_dpp(0, a.i, 0x128, 0xf, 0xf, true); a.f = fmaxf(a.f, b.f);
  return a.f;
}

// ---------------------------------------------------------------------------
// NT GEMM body: C[M,N] = A[M,K] x Bt[N,K] + epilogue. 128xBN tile, BK=64 as
// two BK=32 LDS planes (half the barriers of BK=32, same bank-safe layout,
// same gload16 contiguity). 256 threads, mfma 16x16x32 bf16.
// ---------------------------------------------------------------------------
template <typename OutT, bool GELU, int BN, bool SPLIT>
DEV void gemm_body(
    const u16* __restrict__ A, const u16* __restrict__ Bt, OutT* __restrict__ C,
    int K, int lda, int ldb, int ldc,
    const float* __restrict__ bias,
    const float* __restrict__ resF, const u16* __restrict__ resB, int ldr,
    float scale, long long sA, long long sB, long long sC, long long sR,
    int kSlices, int bx, int by, int z,
    u16* As /*128*64*/, u16* Bs /*BN*64*/)
{
  constexpr int NW = (BN == 128) ? 64 : 32;
  constexpr int NJ = NW / 16;
  constexpr int BH = BN * 32;   // Bs plane size (elems)

  const int bz = z / kSlices;
  const int ks = z - bz * kSlices;
  const int Ksl = K / kSlices;
  const int kbeg = ks * Ksl, kend = kbeg + Ksl;

  A  += (size_t)bz * sA;
  Bt += (size_t)bz * sB;
  if constexpr (SPLIT) C += (size_t)ks * sC;
  else                 C += (size_t)bz * sC;
  const int m0 = by * 128, n0 = bx * BN;
  const int tid = threadIdx.x;
  const int lane = tid & 63, wave = tid >> 6;
  const int wm = (wave >> 1) * 64, wn = (wave & 1) * NW;
  const int m15 = lane & 15, quad = lane >> 4;

  const u16* Ab = A + (size_t)m0 * lda;
  const u16* Bb = Bt + (size_t)n0 * ldb;
  const int r0 = tid >> 2, cc8 = (tid & 3) * 8;

  f32x4 acc[4][NJ];
#pragma unroll
  for (int i = 0; i < 4; i++)
#pragma unroll
    for (int j = 0; j < NJ; j++) acc[i][j] = (f32x4){0.f, 0.f, 0.f, 0.f};

  for (int k0 = kbeg; k0 < kend; k0 += 64) {
    __syncthreads();
#pragma unroll
    for (int h = 0; h < 2; h++) {
      const int kc = k0 + h * 32 + cc8;
      u16* Ah = As + h * 4096;
      gload16(Ab + (size_t)r0 * lda + kc,        Ah + tid * 8);
      gload16(Ab + (size_t)(r0 + 64) * lda + kc, Ah + 2048 + tid * 8);
      u16* Bh = Bs + h * BH;
      gload16(Bb + (size_t)r0 * ldb + kc,        Bh + tid * 8);
      if constexpr (BN == 128)
        gload16(Bb + (size_t)(r0 + 64) * ldb + kc, Bh + 2048 + tid * 8);
    }
    __syncthreads();
#pragma unroll
    for (int h = 0; h < 2; h++) {
      bf16x8 af[4], bfr[NJ];
#pragma unroll
      for (int i = 0; i < 4; i++)
        af[i] = *(const bf16x8*)&As[h * 4096 + (wm + i * 16 + m15) * 32 + quad * 8];
#pragma unroll
      for (int j = 0; j < NJ; j++)
        bfr[j] = *(const bf16x8*)&Bs[h * BH + (wn + j * 16 + m15) * 32 + quad * 8];
#pragma unroll
      for (int i = 0; i < 4; i++)
#pragma unroll
        for (int j = 0; j < NJ; j++)
          acc[i][j] = __builtin_amdgcn_mfma_f32_16x16x32_bf16(af[i], bfr[j], acc[i][j], 0, 0, 0);
    }
  }

  const float* resFb = resF ? resF + (size_t)bz * sR : nullptr;
  const u16*   resBb = resB ? resB + (size_t)bz * sR : nullptr;

#pragma unroll
  for (int i = 0; i < 4; i++) {
    const int rowb = m0 + wm + i * 16 + quad * 4;
#pragma unroll
    for (int r = 0; r < 4; r++) {
      const size_t rowoff = (size_t)(rowb + r) * ldc;
      const size_t resoff = (size_t)(rowb + r) * ldr;
#pragma unroll
      for (int j = 0; j < NJ; j++) {
        const int col = n0 + wn + j * 16 + m15;
        float v = acc[i][j][r] * scale;
        if constexpr (SPLIT) {
          ((u16*)C)[rowoff + col] = f2bf(v);
        } else {
          if (bias) v += bias[col];
          if (GELU) v = fast_gelu(v);
          if (resFb) v += resFb[resoff + col];
          if (resBb) v += bf2f(resBb[resoff + col]);
          if constexpr (sizeof(OutT) == 4) C[rowoff + col] = v;
          else ((u16*)C)[rowoff + col] = f2bf(v);
        }
      }
    }
  }
}

template <typename OutT, bool GELU, int BN, bool SPLIT>
__global__ __launch_bounds__(256, 4) void gemm_nt(
    const u16* __restrict__ A, const u16* __restrict__ Bt, OutT* __restrict__ C,
    int K, int lda, int ldb, int ldc,
    const float* __restrict__ bias,
    const float* __restrict__ resF, const u16* __restrict__ resB, int ldr,
    float scale, long long sA, long long sB, long long sC, long long sR,
    int kSlices)
{
  __shared__ u16 As[128 * 64];
  __shared__ u16 Bs[BN * 64];
  gemm_body<OutT, GELU, BN, SPLIT>(A, Bt, C, K, lda, ldb, ldc, bias, resF, resB,
                                   ldr, scale, sA, sB, sC, sR, kSlices,
                                   blockIdx.x, blockIdx.y, blockIdx.z, As, Bs);
}

// qkv GEMM (24 n-tiles) + kv GEMM (16 n-tiles) in one dispatch. grid (40,32).
__global__ __launch_bounds__(256, 4) void gemm_dual(
    const u16* __restrict__ A1, const u16* __restrict__ B1, u16* __restrict__ C1,
    int ldc1, const float* __restrict__ bias1, int nx1,
    const u16* __restrict__ A2, const u16* __restrict__ B2, u16* __restrict__ C2,
    int ldc2, const float* __restrict__ bias2)
{
  __shared__ u16 As[128 * 64];
  __shared__ u16 Bs[128 * 64];
  const int bx = blockIdx.x;
  if (bx < nx1)
    gemm_body<u16, false, 128, false>(A1, B1, C1, 1024, 1024, 1024, ldc1, bias1,
                                      nullptr, nullptr, 0, 1.0f, 0, 0, 0, 0, 1,
                                      bx, blockIdx.y, 0, As, Bs);
  else
    gemm_body<u16, false, 128, false>(A2, B2, C2, 1024, 1024, 1024, ldc2, bias2,
                                      nullptr, nullptr, 0, 1.0f, 0, 0, 0, 0, 1,
                                      bx - nx1, blockIdx.y, 0, As, Bs);
}

// ---------------------------------------------------------------------------
// mlp2 reduce: outF = sum_{ks<4} partial[ks] + outb(bf16 residual) + b_m2[col]
// ---------------------------------------------------------------------------
__global__ __launch_bounds__(256) void mlp2_reduce_k(
    const u16* __restrict__ part, long long sliceStride,
    const u16* __restrict__ outb, const float* __restrict__ b_m2,
    float* __restrict__ outF)
{
  const size_t i = (size_t)blockIdx.x * 256 + threadIdx.x;
  const int col = (int)((i * 4) & 1023);
  const ushort4 u = ((const ushort4*)outb)[i];
  float4 o;
  o.x = bf2f(u.x) + b_m2[col + 0];
  o.y = bf2f(u.y) + b_m2[col + 1];
  o.z = bf2f(u.z) + b_m2[col + 2];
  o.w = bf2f(u.w) + b_m2[col + 3];
#pragma unroll
  for (int ks = 0; ks < 4; ks++) {
    const ushort4 p = ((const ushort4*)(part + (size_t)ks * sliceStride))[i];
    o.x += bf2f(p.x); o.y += bf2f(p.y); o.z += bf2f(p.z); o.w += bf2f(p.w);
  }
  ((float4*)outF)[i] = o;
}

// ---------------------------------------------------------------------------
// Fused prep: 5 weight transposes (fp32->bf16) + ln1(x) + bf16(z).
// grid: 14336 transpose tiles + 4096 LN rows + 4096 cast rows = 22528 blocks.
// ---------------------------------------------------------------------------
__global__ __launch_bounds__(256) void prep_all_k(
    const float* __restrict__ w_qkv, const float* __restrict__ w_o,
    const float* __restrict__ w_kv,  const float* __restrict__ w_m1,
    const float* __restrict__ w_m2,
    u16* __restrict__ wqkvT, u16* __restrict__ woT, u16* __restrict__ wkvT,
    u16* __restrict__ wm1T,  u16* __restrict__ wm2T,
    const float* __restrict__ x, const float* __restrict__ g1,
    const float* __restrict__ b1, u16* __restrict__ xln,
    const float* __restrict__ z, u16* __restrict__ zb)
{
  __shared__ u16 tile[32][33];
  __shared__ float red[8];
  int idx = blockIdx.x;
  const int t = threadIdx.x;
  if (idx >= 14336) {
    idx -= 14336;
    if (idx >= 4096) {   // z cast
      const size_t i = (size_t)(idx - 4096) * 256 + t;
      const float4 f = ((const float4*)z)[i];
      ushort4 o; o.x = f2bf(f.x); o.y = f2bf(f.y); o.z = f2bf(f.z); o.w = f2bf(f.w);
      ((ushort4*)zb)[i] = o;
      return;
    }
    // layernorm row
    const int row = idx;
    float v[4];
    const float4 f = ((const float4*)(x + (size_t)row * 1024))[t];
    v[0] = f.x; v[1] = f.y; v[2] = f.z; v[3] = f.w;
    float s = v[0] + v[1] + v[2] + v[3];
    float sq = v[0]*v[0] + v[1]*v[1] + v[2]*v[2] + v[3]*v[3];
#pragma unroll
    for (int off = 1; off < 64; off <<= 1) { s += __shfl_xor(s, off); sq += __shfl_xor(sq, off); }
    const int wv = t >> 6;
    if ((t & 63) == 0) { red[wv] = s; red[4 + wv] = sq; }
    __syncthreads();
    s = red[0] + red[1] + red[2] + red[3];
    sq = red[4] + red[5] + red[6] + red[7];
    const float mean = s * (1.0f / 1024.0f);
    const float var = sq * (1.0f / 1024.0f) - mean * mean;
    const float rstd = rsqrtf(var + 1e-5f);
    const int c = t * 4;
    ushort4 o;
    o.x = f2bf((v[0] - mean) * rstd * g1[c + 0] + b1[c + 0]);
    o.y = f2bf((v[1] - mean) * rstd * g1[c + 1] + b1[c + 1]);
    o.z = f2bf((v[2] - mean) * rstd * g1[c + 2] + b1[c + 2]);
    o.w = f2bf((v[3] - mean) * rstd * g1[c + 3] + b1[c + 3]);
    ((ushort4*)(xln + (size_t)row * 1024))[t] = o;
    return;
  }
  // weight transpose tile
  const float* in; u16* out; int gx, ldin, ldout;
  if (idx < 3072)      { in = w_qkv; out = wqkvT; gx = 96;  ldin = 3072; ldout = 1024; }
  else if (idx < 4096) { idx -= 3072; in = w_o;  out = woT;  gx = 32;  ldin = 1024; ldout = 1024; }
  else if (idx < 6144) { idx -= 4096; in = w_kv; out = wkvT; gx = 64;  ldin = 2048; ldout = 1024; }
  else if (idx < 10240){ idx -= 6144; in = w_m1; out = wm1T; gx = 128; ldin = 4096; ldout = 1024; }
  else                 { idx -= 10240; in = w_m2; out = wm2T; gx = 32; ldin = 1024; ldout = 4096; }
  const int bx = idx % gx, by = idx / gx;
  const int tx = t & 31, ty = t >> 5;
  const int xx = bx * 32 + tx;
#pragma unroll
  for (int j = 0; j < 4; j++)
    tile[ty + j * 8][tx] = f2bf(in[(size_t)(by * 32 + ty + j * 8) * ldin + xx]);
  __syncthreads();
  const int x2 = by * 32 + tx;
#pragma unroll
  for (int j = 0; j < 4; j++)
    out[(size_t)(bx * 32 + ty + j * 8) * ldout + x2] = tile[tx][ty + j * 8];
}

// ---------------------------------------------------------------------------
// V pre-transpose for self-attention: per (b,h), [1024 keys][64 d] -> [64 d][1024 keys]
// grid (32, 2, 64)
// ---------------------------------------------------------------------------
__global__ __launch_bounds__(256) void transpose_v_self(
    const u16* __restrict__ qkv, u16* __restrict__ vT)
{
  __shared__ u16 tile[32][33];
  const int z = blockIdx.z, b = z >> 4, h = z & 15;
  const u16* in = qkv + (size_t)b * 1024 * 3072 + 2048 + h * 64;
  u16* out = vT + (size_t)z * 64 * 1024;
  const int tx = threadIdx.x & 31, ty = threadIdx.x >> 5;
  const int key0 = blockIdx.x * 32, d0 = blockIdx.y * 32;
#pragma unroll
  for (int j = 0; j < 4; j++)
    tile[ty + j * 8][tx] = in[(size_t)(key0 + ty + j * 8) * 3072 + d0 + tx];
  __syncthreads();
#pragma unroll
  for (int j = 0; j < 4; j++)
    out[(size_t)(d0 + ty + j * 8) * 1024 + key0 + tx] = tile[tx][ty + j * 8];
}

// ---------------------------------------------------------------------------
// Flash self-attention v3: 64 q-rows/block, grid (16,16,4)=1024 blocks.
// ---------------------------------------------------------------------------
__global__ __launch_bounds__(256, 5) void flash_self_attn3(
    const u16* __restrict__ qkv, const u16* __restrict__ vT, u16* __restrict__ outp)
{
  __shared__ u16 Ks[64 * 72];
  __shared__ u16 Vs[64 * 72];
  __shared__ u16 Ps[4][16 * 72];
  const int b = blockIdx.z, h = blockIdx.y, q0 = blockIdx.x * 64;
  const int tid = threadIdx.x;
  const int lane = tid & 63, w = tid >> 6;
  const int m15 = lane & 15, quad = lane >> 4;
  const float L2E = 1.4426950408889634f;

  const size_t base = (size_t)b * 1024 * 3072;
  const u16* qb  = qkv + base + (size_t)q0 * 3072 + h * 64;
  const u16* kb  = qkv + base + 1024 + h * 64;
  const u16* vtb = vT + (size_t)(b * 16 + h) * 64 * 1024;

  const int r8 = tid >> 3, c8 = (tid & 7) * 8;

  bf16x8 aq[2];
#pragma unroll
  for (int kk = 0; kk < 2; kk++) {
    const bf16x8 raw = *(const bf16x8*)(qb + (size_t)(w * 16 + m15) * 3072 + kk * 32 + quad * 8);
#pragma unroll
    for (int j = 0; j < 8; j++)
      ((u16*)&aq[kk])[j] = f2bf(bf2f(((const u16*)&raw)[j]) * 0.125f);
  }

  const short oneb = (short)0x3F80;
  const bf16x8 ones = {oneb, oneb, oneb, oneb, oneb, oneb, oneb, oneb};

  float mL[4];
  f32x4 lacc;
  f32x4 oacc[4];
#pragma unroll
  for (int r = 0; r < 4; r++) mL[r] = -3.0e38f;
  lacc = (f32x4){0.f, 0.f, 0.f, 0.f};
#pragma unroll
  for (int d = 0; d < 4; d++) oacc[d] = (f32x4){0.f, 0.f, 0.f, 0.f};

  for (int kt = 0; kt < 16; kt++) {
    const int key0 = kt * 64;
    bf16x8 kreg[2], vreg[2];
#pragma unroll
    for (int i = 0; i < 2; i++) {
      kreg[i] = *(const bf16x8*)(kb + (size_t)(key0 + r8 + i * 32) * 3072 + c8);
      vreg[i] = *(const bf16x8*)(vtb + (size_t)(r8 + i * 32) * 1024 + key0 + c8);
    }
    __syncthreads();
#pragma unroll
    for (int i = 0; i < 2; i++) {
      *(bf16x8*)&Ks[(r8 + i * 32) * 72 + c8] = kreg[i];
      *(bf16x8*)&Vs[(r8 + i * 32) * 72 + c8] = vreg[i];
    }
    __syncthreads();

    f32x4 sacc[4];
#pragma unroll
    for (int n = 0; n < 4; n++) sacc[n] = (f32x4){0.f, 0.f, 0.f, 0.f};
#pragma unroll
    for (int kk = 0; kk < 2; kk++)
#pragma unroll
      for (int n = 0; n < 4; n++) {
        const bf16x8 bk = *(const bf16x8*)&Ks[(n * 16 + m15) * 72 + kk * 32 + quad * 8];
        sacc[n] = __builtin_amdgcn_mfma_f32_16x16x32_bf16(aq[kk], bk, sacc[n], 0, 0, 0);
      }

    float al[4];
#pragma unroll
    for (int r = 0; r < 4; r++) {
      float v = fmaxf(fmaxf(sacc[0][r], sacc[1][r]), fmaxf(sacc[2][r], sacc[3][r]));
      v = rowmax16_dpp(v) * L2E;
      const float mnew = fmaxf(mL[r], v);
      al[r] = __builtin_amdgcn_exp2f(mL[r] - mnew);
      mL[r] = mnew;
    }
#pragma unroll
    for (int n = 0; n < 4; n++)
#pragma unroll
      for (int r = 0; r < 4; r++) {
        const float p = __builtin_amdgcn_exp2f(fmaf(sacc[n][r], L2E, -mL[r]));
        Ps[w][(quad * 4 + r) * 72 + n * 16 + m15] = f2bf(p);
      }
#pragma unroll
    for (int r = 0; r < 4; r++) {
      lacc[r] *= al[r];
#pragma unroll
      for (int d = 0; d < 4; d++) oacc[d][r] *= al[r];
    }

    bf16x8 ap[2];
    ap[0] = *(const bf16x8*)&Ps[w][m15 * 72 + quad * 8];
    ap[1] = *(const bf16x8*)&Ps[w][m15 * 72 + 32 + quad * 8];
    lacc = __builtin_amdgcn_mfma_f32_16x16x32_bf16(ap[0], ones, lacc, 0, 0, 0);
    lacc = __builtin_amdgcn_mfma_f32_16x16x32_bf16(ap[1], ones, lacc, 0, 0, 0);
#pragma unroll
    for (int kk = 0; kk < 2; kk++)
#pragma unroll
      for (int d = 0; d < 4; d++) {
        const bf16x8 bv = *(const bf16x8*)&Vs[(d * 16 + m15) * 72 + kk * 32 + quad * 8];
        oacc[d] = __builtin_amdgcn_mfma_f32_16x16x32_bf16(ap[kk], bv, oacc[d], 0, 0, 0);
      }
  }

  u16* ob = outp + (size_t)(b * 1024 + q0 + w * 16 + quad * 4) * 1024 + h * 64 + m15;
#pragma unroll
  for (int r = 0; r < 4; r++) {
    const float inv = 1.0f / lacc[r];
#pragma unroll
    for (int d = 0; d < 4; d++)
      ob[(size_t)r * 1024 + d * 16] = f2bf(oacc[d][r] * inv);
  }
}

// ---------------------------------------------------------------------------
// LayerNorm over last dim (1024), bf16 in -> bf16 out (ln2)
// ---------------------------------------------------------------------------
__global__ __launch_bounds__(256) void layernorm_b_k(
    const u16* __restrict__ x, const float* __restrict__ g, const float* __restrict__ bb,
    u16* __restrict__ y)
{
  const int row = blockIdx.x;
  const int t = threadIdx.x;
  float v[4];
  const ushort4 u = ((const ushort4*)(x + (size_t)row * 1024))[t];
  v[0] = bf2f(u.x); v[1] = bf2f(u.y); v[2] = bf2f(u.z); v[3] = bf2f(u.w);
  float s = v[0] + v[1] + v[2] + v[3];
  float sq = v[0]*v[0] + v[1]*v[1] + v[2]*v[2] + v[3]*v[3];
#pragma unroll
  for (int off = 1; off < 64; off <<= 1) { s += __shfl_xor(s, off); sq += __shfl_xor(sq, off); }
  __shared__ float red[8];
  const int wv = t >> 6;
  if ((t & 63) == 0) { red[wv] = s; red[4 + wv] = sq; }
  __syncthreads();
  s = red[0] + red[1] + red[2] + red[3];
  sq = red[4] + red[5] + red[6] + red[7];
  const float mean = s * (1.0f / 1024.0f);
  const float var = sq * (1.0f / 1024.0f) - mean * mean;
  const float rstd = rsqrtf(var + 1e-5f);
  const int c = t * 4;
  ushort4 o;
  o.x = f2bf((v[0] - mean) * rstd * g[c + 0] + bb[c + 0]);
  o.y = f2bf((v[1] - mean) * rstd * g[c + 1] + bb[c + 1]);
  o.z = f2bf((v[2] - mean) * rstd * g[c + 2] + bb[c + 2]);
  o.w = f2bf((v[3] - mean) * rstd * g[c + 3] + bb[c + 3]);
  ((ushort4*)(y + (size_t)row * 1024))[t] = o;
}

// ---------------------------------------------------------------------------
// Fused: row softmax (4096 blocks) + cross-V transpose (4096 blocks)
// ---------------------------------------------------------------------------
__global__ __launch_bounds__(256) void softmax_vt_k(
    const float* __restrict__ S, u16* __restrict__ P,
    const u16* __restrict__ kv, u16* __restrict__ vT)
{
  __shared__ u16 tile[32][33];
  __shared__ float red[8];
  const int t = threadIdx.x;
  int idx = blockIdx.x;
  if (idx >= 4096) {
    idx -= 4096;
    const int bx = idx & 31, by = (idx >> 5) & 31, bz = idx >> 10;
    const u16* in = kv + 1024 + (size_t)bz * 2097152;   // v = kv[:,1024:2048]
    u16* out = vT + (size_t)bz * 1048576;
    const int tx = t & 31, ty = t >> 5;
    const int x = bx * 32 + tx;
#pragma unroll
    for (int j = 0; j < 4; j++)
      tile[ty + j * 8][tx] = in[(size_t)(by * 32 + ty + j * 8) * 2048 + x];
    __syncthreads();
    const int x2 = by * 32 + tx;
#pragma unroll
    for (int j = 0; j < 4; j++)
      out[(size_t)(bx * 32 + ty + j * 8) * 1024 + x2] = tile[tx][ty + j * 8];
    return;
  }
  const int row = idx;
  const float4 f = ((const float4*)(S + (size_t)row * 1024))[t];
  float mx = fmaxf(fmaxf(f.x, f.y), fmaxf(f.z, f.w));
#pragma unroll
  for (int off = 1; off < 64; off <<= 1) mx = fmaxf(mx, __shfl_xor(mx, off));
  const int wv = t >> 6;
  if ((t & 63) == 0) red[wv] = mx;
  __syncthreads();
  mx = fmaxf(fmaxf(red[0], red[1]), fmaxf(red[2], red[3]));
  float e0 = __expf(f.x - mx), e1 = __expf(f.y - mx), e2 = __expf(f.z - mx), e3 = __expf(f.w - mx);
  float s = e0 + e1 + e2 + e3;
#pragma unroll
  for (int off = 1; off < 64; off <<= 1) s += __shfl_xor(s, off);
  if ((t & 63) == 0) red[4 + wv] = s;
  __syncthreads();
  s = red[4] + red[5] + red[6] + red[7];
  const float inv = 1.0f / s;
  ushort4 o; o.x = f2bf(e0 * inv); o.y = f2bf(e1 * inv); o.z = f2bf(e2 * inv); o.w = f2bf(e3 * inv);
  ((ushort4*)(P + (size_t)row * 1024))[t] = o;
}

// ---------------------------------------------------------------------------
extern "C" void kernel_launch(void* const* d_in, const int* in_sizes, int n_in,
                              void* d_out, int out_size, void* d_ws, size_t ws_size,
                              hipStream_t stream)
{
  const float* x     = (const float*)d_in[0];
  const float* z     = (const float*)d_in[1];
  const float* g1    = (const float*)d_in[2];
  const float* b1    = (const float*)d_in[3];
  const float* w_qkv = (const float*)d_in[4];
  const float* b_qkv = (const float*)d_in[5];
  const float* w_o   = (const float*)d_in[6];
  const float* b_o   = (const float*)d_in[7];
  const float* w_kv  = (const float*)d_in[8];
  const float* b_kv  = (const float*)d_in[9];
  const float* g2    = (const float*)d_in[10];
  const float* b2    = (const float*)d_in[11];
  const float* w_m1  = (const float*)d_in[12];
  const float* b_m1  = (const float*)d_in[13];
  const float* w_m2  = (const float*)d_in[14];
  const float* b_m2  = (const float*)d_in[15];
  float* outF = (float*)d_out;

  char* ws = (char*)d_ws;
  const size_t MB = 1024ull * 1024ull;
  u16*   qkv   = (u16*)(ws + 0);         // 24MB (dead after flash)
  u16*   Pm    = (u16*)(ws + 0);         // 8MB (alias)
  u16*   hm    = (u16*)(ws + 0);         // 32MB (alias)
  u16*   zb    = (u16*)(ws + 24 * MB);   // 8MB (dead after kv GEMM)
  u16*   vTs   = (u16*)(ws + 24 * MB);   // 8MB self-attn V^T (alias of zb)
  u16*   xln   = (u16*)(ws + 32 * MB);   // 8MB; reused as attn_out
  u16*   mpart = (u16*)(ws + 32 * MB);   // 32MB mlp2 partials (alias xln/qbuf/kv)
  u16*   qbuf  = (u16*)(ws + 40 * MB);   // 8MB
  u16*   kv    = (u16*)(ws + 48 * MB);   // 16MB
  float* Ssc   = (float*)(ws + 64 * MB); // 16MB fp32
  u16*   h1    = (u16*)(ws + 64 * MB);   // 8MB (alias, after Ssc dead)
  u16*   outb  = (u16*)(ws + 80 * MB);   // 8MB
  u16*   wqkvT = (u16*)(ws + 88 * MB);   // 6MB
  u16*   woT   = (u16*)(ws + 94 * MB);   // 2MB
  u16*   wkvT  = (u16*)(ws + 96 * MB);   // 4MB
  u16*   wm1T  = (u16*)(ws + 100 * MB);  // 8MB
  u16*   wm2T  = (u16*)(ws + 108 * MB);  // 8MB
  u16*   vT    = (u16*)(ws + 116 * MB);  // 8MB

  dim3 blk(256);
  const long long M1 = 1024 * 1024;

  // fused: 5 weight transposes + ln1(x) + bf16(z)
  hipLaunchKernelGGL(prep_all_k, dim3(22528), blk, 0, stream,
                     w_qkv, w_o, w_kv, w_m1, w_m2, wqkvT, woT, wkvT, wm1T, wm2T,
                     x, g1, b1, xln, z, zb);
  // fused qkv + kv GEMMs (1280 blocks)
  hipLaunchKernelGGL(gemm_dual, dim3(40, 32, 1), blk, 0, stream,
                     xln, wqkvT, qkv, 3072, b_qkv, 24,
                     zb, wkvT, kv, 2048, b_kv);
  // V^T for self-attention (overwrites zb region)
  hipLaunchKernelGGL(transpose_v_self, dim3(32, 2, 64), blk, 0, stream, qkv, vTs);
  // self-attention -> attn_out (reuses xln buffer)
  hipLaunchKernelGGL(flash_self_attn3, dim3(16, 16, 4), blk, 0, stream, qkv, vTs, xln);
  // q = x + attn_out @ w_o + b_o
  hipLaunchKernelGGL((gemm_nt<u16, false, 64, false>), dim3(16, 32, 1), blk, 0, stream,
                     xln, woT, qbuf, 1024, 1024, 1024, 1024,
                     b_o, x, (const u16*)nullptr, 1024, 1.0f, 0LL, 0LL, 0LL, 0LL, 1);
  // cross scores S = q @ k^T / 32  per batch
  hipLaunchKernelGGL((gemm_nt<float, false, 64, false>), dim3(16, 8, 4), blk, 0, stream,
                     qbuf, kv, Ssc, 1024, 1024, 2048, 1024,
                     (const float*)nullptr, (const float*)nullptr, (const u16*)nullptr, 0,
                     0.03125f, M1, 2 * M1, M1, 0LL, 1);
  // fused softmax + cross-V transpose
  hipLaunchKernelGGL(softmax_vt_k, dim3(8192), blk, 0, stream, Ssc, Pm, kv, vT);
  // out = P @ v
  hipLaunchKernelGGL((gemm_nt<u16, false, 64, false>), dim3(16, 8, 4), blk, 0, stream,
                     Pm, vT, outb, 1024, 1024, 1024, 1024,
                     (const float*)nullptr, (const float*)nullptr, (const u16*)nullptr, 0,
                     1.0f, M1, M1, M1, 0LL, 1);
  // h1 = ln2(out)
  hipLaunchKernelGGL(layernorm_b_k, dim3(4096), blk, 0, stream, (const u16*)outb, g2, b2, h1);
  // hm = gelu(h1 @ w_m1 + b_m1)
  hipLaunchKernelGGL((gemm_nt<u16, true, 128, false>), dim3(32, 32, 1), blk, 0, stream,
                     h1, wm1T, hm, 1024, 1024, 1024, 4096,
                     b_m1, (const float*)nullptr, (const u16*)nullptr, 0, 1.0f, 0LL, 0LL, 0LL, 0LL, 1);
  // mlp2 split-K=4: bf16 partials, then fused reduce
  hipLaunchKernelGGL((gemm_nt<u16, false, 128, true>), dim3(8, 32, 4), blk, 0, stream,
                     hm, wm2T, mpart, 4096, 4096, 4096, 1024,
                     (const float*)nullptr, (const float*)nullptr, (const u16*)nullptr, 0,
                     1.0f, 0LL, 0LL, 4LL * M1, 0LL, 4);
  hipLaunchKernelGGL(mlp2_reduce_k, dim3(4096), blk, 0, stream,
                     mpart, 4LL * M1, outb, b_m2, outF);
}